// Round 10
// baseline (132.232 us; speedup 1.0000x reference)
//
#include <hip/hip_runtime.h>
#include <hip/hip_bf16.h>

#define H 4
#define C 32
#define CQ 128
#define NSEQ 256
#define HC 128   // H*C

typedef __bf16 bf16;
typedef __bf16 bf16x8 __attribute__((ext_vector_type(8)));
typedef __bf16 bf16x4 __attribute__((ext_vector_type(4)));
typedef float f32x4 __attribute__((ext_vector_type(4)));

#define MFMA16(a, b, c) __builtin_amdgcn_mfma_f32_16x16x32_bf16(a, b, c, 0, 0, 0)

#define LOG2E 1.4426950408889634f

// ---------------------------------------------------------------------------
// Convert the 5 weight matrices (each 128x128 f32) to bf16 in ws.
// ---------------------------------------------------------------------------
__global__ __launch_bounds__(256) void prep_weights(const float* __restrict__ wq,
                                                    const float* __restrict__ wk,
                                                    const float* __restrict__ wv,
                                                    const float* __restrict__ wg,
                                                    const float* __restrict__ wo,
                                                    bf16* __restrict__ dst) {
    const int m = blockIdx.y;
    const float* src = (m == 0) ? wq : (m == 1) ? wk : (m == 2) ? wv : (m == 3) ? wg : wo;
    int i = blockIdx.x * 256 + threadIdx.x;  // 4096 float4's per matrix
    float4 v = ((const float4*)src)[i];
    bf16x4 b = {(bf16)v.x, (bf16)v.y, (bf16)v.z, (bf16)v.w};
    ((bf16x4*)(dst + (size_t)m * 16384))[i] = b;
}

// ---------------------------------------------------------------------------
// Dual projection v3 — SWAPPED operands: A = weight strip (from LDS, read
// once per wave), B = x rows (direct from global f32). D-layout then gives
// each lane 4 CONSECUTIVE output features -> bf16x4 stores (4x fewer store
// instrs than v2's scalar stores), and the per-wave register set is small
// (A 32 + acc 8 VGPR) -> high occupancy. 512 thr = 8 waves, 1 strip each.
// mode 0: q = (q_x@w_q^T)*(qscale*log2e), g = sigmoid(q_x@w_g^T)
// mode 1: k = kv_x@w_k^T, v = kv_x@w_v^T
// ---------------------------------------------------------------------------
__global__ __launch_bounds__(512) void proj_all(const float* __restrict__ qx,
                                                const float* __restrict__ kvx,
                                                const bf16* __restrict__ wbf,
                                                bf16* __restrict__ qo,
                                                bf16* __restrict__ go,
                                                bf16* __restrict__ ko,
                                                bf16* __restrict__ vo) {
    __shared__ bf16 w1s[128][136];
    __shared__ bf16 w2s[128][136];

    const int t = threadIdx.x;
    const int mode = blockIdx.y;

    const float* x = mode ? kvx : qx;
    const bf16* w1 = wbf + (mode ? 1 : 0) * 16384;  // w_k : w_q
    const bf16* w2 = wbf + (mode ? 2 : 3) * 16384;  // w_v : w_g
    bf16* o1 = mode ? ko : qo;
    bf16* o2 = mode ? vo : go;

    // stage both weight matrices (4 iters of bf16x8 per thread)
    #pragma unroll
    for (int i = t; i < 2048; i += 512) {
        int row = i >> 4, col = (i & 15) * 8;
        *(bf16x8*)&w1s[row][col] = *(const bf16x8*)&w1[row * CQ + col];
        *(bf16x8*)&w2s[row][col] = *(const bf16x8*)&w2[row * CQ + col];
    }
    __syncthreads();

    const int w = t >> 6;   // feature strip 0..7 (features w*16 .. w*16+15)
    const int l = t & 63, lr = l & 15, lg = l >> 4;

    // A-fragments: this wave's strip of both matrices (read once)
    bf16x8 a1[4], a2[4];
    #pragma unroll
    for (int ks = 0; ks < 4; ks++) {
        a1[ks] = *(const bf16x8*)&w1s[w * 16 + lr][ks * 32 + lg * 8];
        a2[ks] = *(const bf16x8*)&w2s[w * 16 + lr][ks * 32 + lg * 8];
    }

    const float qscale = 0.17677669529663687f * LOG2E;  // 1/sqrt(32) * log2e

    // 16 x-row tiles of 16 rows each (256 rows per block)
    for (int it = 0; it < 16; it++) {
        const int row0 = blockIdx.x * 256 + it * 16;

        // B-fragments: x rows direct from global f32
        bf16x8 b[4];
        #pragma unroll
        for (int ks = 0; ks < 4; ks++) {
            const float* p = x + (size_t)(row0 + lr) * CQ + ks * 32 + lg * 8;
            float4 lo = *(const float4*)p;
            float4 hi = *(const float4*)(p + 4);
            b[ks] = (bf16x8){(bf16)lo.x, (bf16)lo.y, (bf16)lo.z, (bf16)lo.w,
                             (bf16)hi.x, (bf16)hi.y, (bf16)hi.z, (bf16)hi.w};
        }

        f32x4 acc1 = (f32x4)0.f, acc2 = (f32x4)0.f;
        #pragma unroll
        for (int ks = 0; ks < 4; ks++) {
            acc1 = MFMA16(a1[ks], b[ks], acc1);
            acc2 = MFMA16(a2[ks], b[ks], acc2);
        }

        // D: row = feature-in-strip = lg*4 + r, col = x-row = lr
        // -> per lane: 4 consecutive features of one x-row
        bf16x4 st1, st2;
        #pragma unroll
        for (int r = 0; r < 4; r++) {
            float v1 = acc1[r], v2 = acc2[r];
            if (mode == 0) {
                v1 *= qscale;
                v2 = __builtin_amdgcn_rcpf(1.f + __builtin_amdgcn_exp2f(-v2 * LOG2E));
            }
            st1[r] = (bf16)v1;
            st2[r] = (bf16)v2;
        }
        const size_t obase = (size_t)(row0 + lr) * HC + w * 16 + lg * 4;
        *(bf16x4*)&o1[obase] = st1;
        *(bf16x4*)&o2[obase] = st2;
    }
}

// ---------------------------------------------------------------------------
// Attention per (qc, n1, h): 64 q-rows x 256 k, C=32. Linear 4096-block grid
// with chunked XCD swizzle so the 4 qc-blocks of one (n1,h) land on the SAME
// XCD. Scores in log2 domain; softmax via exp2; PV in two 128-k halves
// through a per-wave P tile. (Unchanged — proven.)
// ---------------------------------------------------------------------------
__global__ __launch_bounds__(256) void attn_kernel(const bf16* __restrict__ qw,
                                                   const bf16* __restrict__ kw,
                                                   const bf16* __restrict__ vw,
                                                   const bf16* __restrict__ gw,
                                                   const float* __restrict__ pair_bias,
                                                   const float* __restrict__ mask_bias,
                                                   bf16* __restrict__ ow) {
    const int wg = blockIdx.x;
    const int swz = ((wg & 7) << 9) + (wg >> 3);
    const int qc = swz & 3;
    const int n1 = (swz >> 2) & 255;
    const int h = swz >> 10;

    __shared__ bf16 klds[256][40];   // K slice [k][c], stride 20 dw
    __shared__ bf16 vts[32][256];    // V^T, col = k ^ 16*((c>>3)&3) ^ 8*(c&7)
    __shared__ bf16 ps[4][16][132];  // per-wave P tile

    const int t = threadIdx.x;

    {
        const size_t base = ((size_t)n1 * NSEQ) * HC + (size_t)h * C;
        const int rr = t >> 2, cc4 = t & 3, ch = cc4 * 8;
        #pragma unroll
        for (int p = 0; p < 4; p++) {
            int row = p * 64 + rr;
            bf16x8 kv = *(const bf16x8*)&kw[base + (size_t)row * HC + ch];
            *(bf16x8*)&klds[row][ch] = kv;
            bf16x8 vv = *(const bf16x8*)&vw[base + (size_t)row * HC + ch];
            #pragma unroll
            for (int j = 0; j < 8; j++) {
                int colw = row ^ (cc4 << 4) ^ (j << 3);
                vts[ch + j][colw] = vv[j];
            }
        }
    }

    const int w = t >> 6, l = t & 63, lr = l & 15, lg = l >> 4;
    const int qbase = qc * 64 + w * 16;

    bf16x8 qf = *(const bf16x8*)&qw[((size_t)(n1 * NSEQ + qbase + lr)) * HC + h * C + lg * 8];

    const float* pb = pair_bias + (size_t)h * NSEQ * NSEQ;
    const float* mb = mask_bias + (size_t)n1 * NSEQ;

    __syncthreads();

    f32x4 s[16];
    #pragma unroll
    for (int kt = 0; kt < 16; kt++) {
        float mbk = mb[kt * 16 + lr] * LOG2E;
        #pragma unroll
        for (int r = 0; r < 4; r++)
            s[kt][r] = fmaf(pb[(size_t)(qbase + lg * 4 + r) * NSEQ + kt * 16 + lr],
                            LOG2E, mbk);
    }
    #pragma unroll
    for (int kt = 0; kt < 16; kt++) {
        bf16x8 kf = *(const bf16x8*)&klds[kt * 16 + lr][lg * 8];
        s[kt] = MFMA16(qf, kf, s[kt]);
    }

    float pinv[4];
    #pragma unroll
    for (int r = 0; r < 4; r++) {
        float mx = s[0][r];
        #pragma unroll
        for (int kt = 1; kt < 16; kt++) mx = fmaxf(mx, s[kt][r]);
        #pragma unroll
        for (int msk = 8; msk >= 1; msk >>= 1) mx = fmaxf(mx, __shfl_xor(mx, msk, 64));
        float sum = 0.f;
        #pragma unroll
        for (int kt = 0; kt < 16; kt++) {
            float e = __builtin_amdgcn_exp2f(s[kt][r] - mx);
            s[kt][r] = e;
            sum += e;
        }
        #pragma unroll
        for (int msk = 8; msk >= 1; msk >>= 1) sum += __shfl_xor(sum, msk, 64);
        pinv[r] = __builtin_amdgcn_rcpf(sum);
    }

    f32x4 o[2];
    o[0] = (f32x4)0.f;
    o[1] = (f32x4)0.f;
    #pragma unroll
    for (int hf = 0; hf < 2; hf++) {
        #pragma unroll
        for (int kt2 = 0; kt2 < 8; kt2++) {
            #pragma unroll
            for (int r = 0; r < 4; r++)
                ps[w][lg * 4 + r][kt2 * 16 + lr] = (bf16)(s[hf * 8 + kt2][r] * pinv[r]);
        }
        #pragma unroll
        for (int kh = 0; kh < 4; kh++) {
            bf16x8 pf = *(const bf16x8*)&ps[w][lr][kh * 32 + lg * 8];
            #pragma unroll
            for (int ct = 0; ct < 2; ct++) {
                int g2 = (2 * ct + (lr >> 3)) & 3;
                int col0 = (hf * 128 + kh * 32 + lg * 8) ^ (g2 << 4) ^ ((lr & 7) << 3);
                bf16x8 vf = *(const bf16x8*)&vts[ct * 16 + lr][col0];
                o[ct] = MFMA16(pf, vf, o[ct]);
            }
        }
    }

    #pragma unroll
    for (int ct = 0; ct < 2; ct++) {
        #pragma unroll
        for (int r = 0; r < 4; r++) {
            size_t idx = ((size_t)(n1 * NSEQ + qbase + lg * 4 + r)) * HC + (size_t)h * C +
                         ct * 16 + lr;
            float gv = (float)gw[idx];
            ow[idx] = (bf16)(o[ct][r] * gv);
        }
    }
}

// ---------------------------------------------------------------------------
// Output projection v3 — SWAPPED operands: A = w_o strip from LDS, B = og
// rows from global bf16. Per lane: 4 consecutive out channels -> float4
// stores. 512 thr = 8 waves, 1 strip each; 128 rows per block (8 tiles).
// ---------------------------------------------------------------------------
__global__ __launch_bounds__(512) void out_proj(const bf16* __restrict__ og,
                                                const bf16* __restrict__ wo,
                                                float* __restrict__ out) {
    __shared__ bf16 ws[128][136];
    const int t = threadIdx.x;

    #pragma unroll
    for (int i = t; i < 2048; i += 512) {
        int row = i >> 4, col = (i & 15) * 8;
        *(bf16x8*)&ws[row][col] = *(const bf16x8*)&wo[row * CQ + col];
    }
    __syncthreads();

    const int w = t >> 6, l = t & 63, lr = l & 15, lg = l >> 4;

    bf16x8 a[4];
    #pragma unroll
    for (int ks = 0; ks < 4; ks++)
        a[ks] = *(const bf16x8*)&ws[w * 16 + lr][ks * 32 + lg * 8];

    for (int it = 0; it < 8; it++) {
        const int row0 = blockIdx.x * 128 + it * 16;

        bf16x8 b[4];
        #pragma unroll
        for (int ks = 0; ks < 4; ks++)
            b[ks] = *(const bf16x8*)&og[(size_t)(row0 + lr) * HC + ks * 32 + lg * 8];

        f32x4 acc = (f32x4)0.f;
        #pragma unroll
        for (int ks = 0; ks < 4; ks++)
            acc = MFMA16(a[ks], b[ks], acc);

        // D: row = out-channel-in-strip = lg*4 + r, col = m-row = lr
        *(float4*)&out[(size_t)(row0 + lr) * CQ + w * 16 + lg * 4] =
            (float4){acc[0], acc[1], acc[2], acc[3]};
    }
}

// ---------------------------------------------------------------------------
extern "C" void kernel_launch(void* const* d_in, const int* in_sizes, int n_in,
                              void* d_out, int out_size, void* d_ws, size_t ws_size,
                              hipStream_t stream) {
    const float* q_x = (const float*)d_in[0];
    const float* kv_x = (const float*)d_in[1];
    const float* mask_bias = (const float*)d_in[2];
    const float* pair_bias = (const float*)d_in[3];
    const float* w_q = (const float*)d_in[4];
    const float* w_k = (const float*)d_in[5];
    const float* w_v = (const float*)d_in[6];
    const float* w_g = (const float*)d_in[7];
    const float* w_o = (const float*)d_in[8];

    const size_t M = (size_t)NSEQ * NSEQ;  // 65536
    bf16* wbf = (bf16*)d_ws;               // [5][16384] bf16: q,k,v,g,o
    bf16* qws = wbf + 5 * 16384;
    bf16* gws = qws + M * HC;
    bf16* kws = gws + M * HC;
    bf16* vws = kws + M * HC;
    bf16* ows = vws + M * HC;

    prep_weights<<<dim3(16, 5), 256, 0, stream>>>(w_q, w_k, w_v, w_g, w_o, wbf);
    proj_all<<<dim3(256, 2), 512, 0, stream>>>(q_x, kv_x, wbf, qws, gws, kws, vws);
    attn_kernel<<<dim3(4096), 256, 0, stream>>>(qws, kws, vws, gws, pair_bias,
                                                mask_bias, ows);
    out_proj<<<dim3(512), 512, 0, stream>>>(ows, wbf + 4 * 16384, (float*)d_out);
}

// Round 11
// 87.175 us; speedup vs baseline: 1.5169x; 1.5169x over previous
//
#include <hip/hip_runtime.h>
#include <hip/hip_bf16.h>

#define H 4
#define C 32
#define CQ 128
#define NSEQ 256
#define HC 128   // H*C

typedef __bf16 bf16;
typedef __bf16 bf16x8 __attribute__((ext_vector_type(8)));
typedef __bf16 bf16x4 __attribute__((ext_vector_type(4)));
typedef float f32x4 __attribute__((ext_vector_type(4)));

#define MFMA16(a, b, c) __builtin_amdgcn_mfma_f32_16x16x32_bf16(a, b, c, 0, 0, 0)

#define LOG2E 1.4426950408889634f

__device__ __forceinline__ bf16x8 cvt8(float4 a, float4 b) {
    return (bf16x8){(bf16)a.x, (bf16)a.y, (bf16)a.z, (bf16)a.w,
                    (bf16)b.x, (bf16)b.y, (bf16)b.z, (bf16)b.w};
}

// ---------------------------------------------------------------------------
// Convert the 5 weight matrices (each 128x128 f32) to bf16 in ws.
// ---------------------------------------------------------------------------
__global__ __launch_bounds__(256) void prep_weights(const float* __restrict__ wq,
                                                    const float* __restrict__ wk,
                                                    const float* __restrict__ wv,
                                                    const float* __restrict__ wg,
                                                    const float* __restrict__ wo,
                                                    bf16* __restrict__ dst) {
    const int m = blockIdx.y;
    const float* src = (m == 0) ? wq : (m == 1) ? wk : (m == 2) ? wv : (m == 3) ? wg : wo;
    int i = blockIdx.x * 256 + threadIdx.x;  // 4096 float4's per matrix
    float4 v = ((const float4*)src)[i];
    bf16x4 b = {(bf16)v.x, (bf16)v.y, (bf16)v.z, (bf16)v.w};
    ((bf16x4*)(dst + (size_t)m * 16384))[i] = b;
}

// ---------------------------------------------------------------------------
// Dual projection v4: swapped operands (A = weight strip from LDS, verified
// R10 store layout) + x-tiles staged in LDS, double-buffered with register
// prefetch (T3-minimum schedule). 256 rows/block, 4 iters of 64 rows.
// Per iter/wave: 16 ds_read_b128 + 32 MFMA + 8 bf16x4 stores; staging via
// 4 float4 global loads issued BEFORE compute, written to LDS after.
// unroll 1 on the it-loop: prevents cross-iteration hoisting (R9's VGPR=196).
// mode 0: q = (q_x@w_q^T)*(qscale*log2e), g = sigmoid(q_x@w_g^T)
// mode 1: k = kv_x@w_k^T, v = kv_x@w_v^T
// ---------------------------------------------------------------------------
__global__ __launch_bounds__(512) void proj_all(const float* __restrict__ qx,
                                                const float* __restrict__ kvx,
                                                const bf16* __restrict__ wbf,
                                                bf16* __restrict__ qo,
                                                bf16* __restrict__ go,
                                                bf16* __restrict__ ko,
                                                bf16* __restrict__ vo) {
    __shared__ bf16 w1s[128][136];
    __shared__ bf16 w2s[128][136];
    __shared__ bf16 xs[2][64][136];

    const int t = threadIdx.x;
    const int mode = blockIdx.y;

    const float* x = mode ? kvx : qx;
    const bf16* w1 = wbf + (mode ? 1 : 0) * 16384;  // w_k : w_q
    const bf16* w2 = wbf + (mode ? 2 : 3) * 16384;  // w_v : w_g
    bf16* o1 = mode ? ko : qo;
    bf16* o2 = mode ? vo : go;

    const int row_blk = blockIdx.x * 256;
    const int sr = t >> 3, sc = (t & 7) * 16;  // staging coords: 8 thr/row

    // stage both weight matrices (4 iters of bf16x8 per thread)
    #pragma unroll
    for (int i = t; i < 2048; i += 512) {
        int row = i >> 4, col = (i & 15) * 8;
        *(bf16x8*)&w1s[row][col] = *(const bf16x8*)&w1[row * CQ + col];
        *(bf16x8*)&w2s[row][col] = *(const bf16x8*)&w2[row * CQ + col];
    }
    // stage x tile 0 (64 rows x 128 f32 -> bf16; coalesced 64B/thread)
    {
        const float* p = x + (size_t)(row_blk + sr) * CQ + sc;
        float4 v0 = *(const float4*)p, v1 = *(const float4*)(p + 4);
        float4 v2 = *(const float4*)(p + 8), v3 = *(const float4*)(p + 12);
        *(bf16x8*)&xs[0][sr][sc] = cvt8(v0, v1);
        *(bf16x8*)&xs[0][sr][sc + 8] = cvt8(v2, v3);
    }
    __syncthreads();

    const int w = t >> 6, l = t & 63, lr = l & 15, lg = l >> 4;

    // A-fragments: this wave's feature strip of both matrices (read once)
    bf16x8 a1[4], a2[4];
    #pragma unroll
    for (int ks = 0; ks < 4; ks++) {
        a1[ks] = *(const bf16x8*)&w1s[w * 16 + lr][ks * 32 + lg * 8];
        a2[ks] = *(const bf16x8*)&w2s[w * 16 + lr][ks * 32 + lg * 8];
    }

    const float qscale = 0.17677669529663687f * LOG2E;  // 1/sqrt(32) * log2e

    #pragma unroll 1
    for (int it = 0; it < 4; it++) {
        const int cur = it & 1;

        // prefetch next 64-row tile into registers (issued before compute)
        float4 n0, n1, n2, n3;
        if (it < 3) {
            const float* p = x + (size_t)(row_blk + (it + 1) * 64 + sr) * CQ + sc;
            n0 = *(const float4*)p;
            n1 = *(const float4*)(p + 4);
            n2 = *(const float4*)(p + 8);
            n3 = *(const float4*)(p + 12);
        }

        // compute current tile: 4 row-tiles of 16
        #pragma unroll
        for (int rt = 0; rt < 4; rt++) {
            bf16x8 b[4];
            #pragma unroll
            for (int ks = 0; ks < 4; ks++)
                b[ks] = *(const bf16x8*)&xs[cur][rt * 16 + lr][ks * 32 + lg * 8];

            f32x4 acc1 = (f32x4)0.f, acc2 = (f32x4)0.f;
            #pragma unroll
            for (int ks = 0; ks < 4; ks++) {
                acc1 = MFMA16(a1[ks], b[ks], acc1);
                acc2 = MFMA16(a2[ks], b[ks], acc2);
            }

            // D: row = feature-in-strip = lg*4+r, col = x-row = lr (verified R10)
            bf16x4 st1, st2;
            #pragma unroll
            for (int r = 0; r < 4; r++) {
                float v1 = acc1[r], v2 = acc2[r];
                if (mode == 0) {
                    v1 *= qscale;
                    v2 = __builtin_amdgcn_rcpf(1.f + __builtin_amdgcn_exp2f(-v2 * LOG2E));
                }
                st1[r] = (bf16)v1;
                st2[r] = (bf16)v2;
            }
            const size_t obase =
                (size_t)(row_blk + it * 64 + rt * 16 + lr) * HC + w * 16 + lg * 4;
            *(bf16x4*)&o1[obase] = st1;
            *(bf16x4*)&o2[obase] = st2;
        }

        // write prefetched tile to the other buffer
        if (it < 3) {
            *(bf16x8*)&xs[cur ^ 1][sr][sc] = cvt8(n0, n1);
            *(bf16x8*)&xs[cur ^ 1][sr][sc + 8] = cvt8(n2, n3);
        }
        __syncthreads();
    }
}

// ---------------------------------------------------------------------------
// Attention per (qc, n1, h): 64 q-rows x 256 k, C=32. Linear 4096-block grid
// with chunked XCD swizzle so the 4 qc-blocks of one (n1,h) land on the SAME
// XCD. Scores in log2 domain; softmax via exp2; PV in two 128-k halves
// through a per-wave P tile. (Unchanged — proven.)
// ---------------------------------------------------------------------------
__global__ __launch_bounds__(256) void attn_kernel(const bf16* __restrict__ qw,
                                                   const bf16* __restrict__ kw,
                                                   const bf16* __restrict__ vw,
                                                   const bf16* __restrict__ gw,
                                                   const float* __restrict__ pair_bias,
                                                   const float* __restrict__ mask_bias,
                                                   bf16* __restrict__ ow) {
    const int wg = blockIdx.x;
    const int swz = ((wg & 7) << 9) + (wg >> 3);
    const int qc = swz & 3;
    const int n1 = (swz >> 2) & 255;
    const int h = swz >> 10;

    __shared__ bf16 klds[256][40];   // K slice [k][c], stride 20 dw
    __shared__ bf16 vts[32][256];    // V^T, col = k ^ 16*((c>>3)&3) ^ 8*(c&7)
    __shared__ bf16 ps[4][16][132];  // per-wave P tile

    const int t = threadIdx.x;

    {
        const size_t base = ((size_t)n1 * NSEQ) * HC + (size_t)h * C;
        const int rr = t >> 2, cc4 = t & 3, ch = cc4 * 8;
        #pragma unroll
        for (int p = 0; p < 4; p++) {
            int row = p * 64 + rr;
            bf16x8 kv = *(const bf16x8*)&kw[base + (size_t)row * HC + ch];
            *(bf16x8*)&klds[row][ch] = kv;
            bf16x8 vv = *(const bf16x8*)&vw[base + (size_t)row * HC + ch];
            #pragma unroll
            for (int j = 0; j < 8; j++) {
                int colw = row ^ (cc4 << 4) ^ (j << 3);
                vts[ch + j][colw] = vv[j];
            }
        }
    }

    const int w = t >> 6, l = t & 63, lr = l & 15, lg = l >> 4;
    const int qbase = qc * 64 + w * 16;

    bf16x8 qf = *(const bf16x8*)&qw[((size_t)(n1 * NSEQ + qbase + lr)) * HC + h * C + lg * 8];

    const float* pb = pair_bias + (size_t)h * NSEQ * NSEQ;
    const float* mb = mask_bias + (size_t)n1 * NSEQ;

    __syncthreads();

    f32x4 s[16];
    #pragma unroll
    for (int kt = 0; kt < 16; kt++) {
        float mbk = mb[kt * 16 + lr] * LOG2E;
        #pragma unroll
        for (int r = 0; r < 4; r++)
            s[kt][r] = fmaf(pb[(size_t)(qbase + lg * 4 + r) * NSEQ + kt * 16 + lr],
                            LOG2E, mbk);
    }
    #pragma unroll
    for (int kt = 0; kt < 16; kt++) {
        bf16x8 kf = *(const bf16x8*)&klds[kt * 16 + lr][lg * 8];
        s[kt] = MFMA16(qf, kf, s[kt]);
    }

    float pinv[4];
    #pragma unroll
    for (int r = 0; r < 4; r++) {
        float mx = s[0][r];
        #pragma unroll
        for (int kt = 1; kt < 16; kt++) mx = fmaxf(mx, s[kt][r]);
        #pragma unroll
        for (int msk = 8; msk >= 1; msk >>= 1) mx = fmaxf(mx, __shfl_xor(mx, msk, 64));
        float sum = 0.f;
        #pragma unroll
        for (int kt = 0; kt < 16; kt++) {
            float e = __builtin_amdgcn_exp2f(s[kt][r] - mx);
            s[kt][r] = e;
            sum += e;
        }
        #pragma unroll
        for (int msk = 8; msk >= 1; msk >>= 1) sum += __shfl_xor(sum, msk, 64);
        pinv[r] = __builtin_amdgcn_rcpf(sum);
    }

    f32x4 o[2];
    o[0] = (f32x4)0.f;
    o[1] = (f32x4)0.f;
    #pragma unroll
    for (int hf = 0; hf < 2; hf++) {
        #pragma unroll
        for (int kt2 = 0; kt2 < 8; kt2++) {
            #pragma unroll
            for (int r = 0; r < 4; r++)
                ps[w][lg * 4 + r][kt2 * 16 + lr] = (bf16)(s[hf * 8 + kt2][r] * pinv[r]);
        }
        #pragma unroll
        for (int kh = 0; kh < 4; kh++) {
            bf16x8 pf = *(const bf16x8*)&ps[w][lr][kh * 32 + lg * 8];
            #pragma unroll
            for (int ct = 0; ct < 2; ct++) {
                int g2 = (2 * ct + (lr >> 3)) & 3;
                int col0 = (hf * 128 + kh * 32 + lg * 8) ^ (g2 << 4) ^ ((lr & 7) << 3);
                bf16x8 vf = *(const bf16x8*)&vts[ct * 16 + lr][col0];
                o[ct] = MFMA16(pf, vf, o[ct]);
            }
        }
    }

    #pragma unroll
    for (int ct = 0; ct < 2; ct++) {
        #pragma unroll
        for (int r = 0; r < 4; r++) {
            size_t idx = ((size_t)(n1 * NSEQ + qbase + lg * 4 + r)) * HC + (size_t)h * C +
                         ct * 16 + lr;
            float gv = (float)gw[idx];
            ow[idx] = (bf16)(o[ct][r] * gv);
        }
    }
}

// ---------------------------------------------------------------------------
// Output projection v4: swapped operands + og tiles staged in LDS, double-
// buffered (same schedule as proj v4; og is bf16 so prefetch = 2 bf16x8).
// float4 stores (verified R10 layout). 256 rows/block.
// ---------------------------------------------------------------------------
__global__ __launch_bounds__(512) void out_proj(const bf16* __restrict__ og,
                                                const bf16* __restrict__ wo,
                                                float* __restrict__ out) {
    __shared__ bf16 ws[128][136];
    __shared__ bf16 xs[2][64][136];

    const int t = threadIdx.x;
    const int row_blk = blockIdx.x * 256;
    const int sr = t >> 3, sc = (t & 7) * 16;

    #pragma unroll
    for (int i = t; i < 2048; i += 512) {
        int row = i >> 4, col = (i & 15) * 8;
        *(bf16x8*)&ws[row][col] = *(const bf16x8*)&wo[row * CQ + col];
    }
    {
        const bf16* p = og + (size_t)(row_blk + sr) * HC + sc;
        *(bf16x8*)&xs[0][sr][sc] = *(const bf16x8*)p;
        *(bf16x8*)&xs[0][sr][sc + 8] = *(const bf16x8*)(p + 8);
    }
    __syncthreads();

    const int w = t >> 6, l = t & 63, lr = l & 15, lg = l >> 4;

    bf16x8 a[4];
    #pragma unroll
    for (int ks = 0; ks < 4; ks++)
        a[ks] = *(const bf16x8*)&ws[w * 16 + lr][ks * 32 + lg * 8];

    #pragma unroll 1
    for (int it = 0; it < 4; it++) {
        const int cur = it & 1;

        bf16x8 m0, m1;
        if (it < 3) {
            const bf16* p = og + (size_t)(row_blk + (it + 1) * 64 + sr) * HC + sc;
            m0 = *(const bf16x8*)p;
            m1 = *(const bf16x8*)(p + 8);
        }

        #pragma unroll
        for (int rt = 0; rt < 4; rt++) {
            bf16x8 b[4];
            #pragma unroll
            for (int ks = 0; ks < 4; ks++)
                b[ks] = *(const bf16x8*)&xs[cur][rt * 16 + lr][ks * 32 + lg * 8];

            f32x4 acc = (f32x4)0.f;
            #pragma unroll
            for (int ks = 0; ks < 4; ks++)
                acc = MFMA16(a[ks], b[ks], acc);

            *(float4*)&out[(size_t)(row_blk + it * 64 + rt * 16 + lr) * CQ + w * 16 + lg * 4] =
                (float4){acc[0], acc[1], acc[2], acc[3]};
        }

        if (it < 3) {
            *(bf16x8*)&xs[cur ^ 1][sr][sc] = m0;
            *(bf16x8*)&xs[cur ^ 1][sr][sc + 8] = m1;
        }
        __syncthreads();
    }
}

// ---------------------------------------------------------------------------
extern "C" void kernel_launch(void* const* d_in, const int* in_sizes, int n_in,
                              void* d_out, int out_size, void* d_ws, size_t ws_size,
                              hipStream_t stream) {
    const float* q_x = (const float*)d_in[0];
    const float* kv_x = (const float*)d_in[1];
    const float* mask_bias = (const float*)d_in[2];
    const float* pair_bias = (const float*)d_in[3];
    const float* w_q = (const float*)d_in[4];
    const float* w_k = (const float*)d_in[5];
    const float* w_v = (const float*)d_in[6];
    const float* w_g = (const float*)d_in[7];
    const float* w_o = (const float*)d_in[8];

    const size_t M = (size_t)NSEQ * NSEQ;  // 65536
    bf16* wbf = (bf16*)d_ws;               // [5][16384] bf16: q,k,v,g,o
    bf16* qws = wbf + 5 * 16384;
    bf16* gws = qws + M * HC;
    bf16* kws = gws + M * HC;
    bf16* vws = kws + M * HC;
    bf16* ows = vws + M * HC;

    prep_weights<<<dim3(16, 5), 256, 0, stream>>>(w_q, w_k, w_v, w_g, w_o, wbf);
    proj_all<<<dim3(256, 2), 512, 0, stream>>>(q_x, kv_x, wbf, qws, gws, kws, vws);
    attn_kernel<<<dim3(4096), 256, 0, stream>>>(qws, kws, vws, gws, pair_bias,
                                                mask_bias, ows);
    out_proj<<<dim3(256), 512, 0, stream>>>(ows, wbf + 4 * 16384, (float*)d_out);
}